// Round 11
// baseline (302.185 us; speedup 1.0000x reference)
//
#include <hip/hip_runtime.h>
#include <hip/hip_bf16.h>
#include <stdint.h>

// Problem constants
#define B_    2
#define S_    2048
#define D_    2048
#define H_    32
#define KVH_  4
#define HD_   64
#define QKVN  2560   // H*HD + 2*KVH*HD

typedef __bf16 bf16_t;
typedef __bf16 bf16x8 __attribute__((ext_vector_type(8)));
typedef __bf16 bf16x4 __attribute__((ext_vector_type(4)));
typedef __bf16 bf16x2 __attribute__((ext_vector_type(2)));
typedef float  f32x4  __attribute__((ext_vector_type(4)));
typedef float  f32x16 __attribute__((ext_vector_type(16)));
typedef int    i32x4  __attribute__((ext_vector_type(4)));

#define MFMA16(a, b, c) __builtin_amdgcn_mfma_f32_16x16x32_bf16(a, b, c, 0, 0, 0)
#define MFMA32(a, b, c) __builtin_amdgcn_mfma_f32_32x32x16_bf16(a, b, c, 0, 0, 0)

// async global->LDS, 16B per lane.
__device__ __forceinline__ void gld16(const void* g, void* l) {
  __builtin_amdgcn_global_load_lds(
      (const __attribute__((address_space(1))) uint32_t*)(uintptr_t)g,
      (__attribute__((address_space(3))) uint32_t*)(uint32_t)(uintptr_t)l,
      16, 0, 0);
}

// pack two f32 -> u32 of 2 bf16 (RNE via scalar casts)
__device__ __forceinline__ int pkbf(float a, float b) {
  bf16x2 t = { (bf16_t)a, (bf16_t)b };
  return __builtin_bit_cast(int, t);
}

// raw v_exp_f32 (2^x); scores bounded, masked lanes -1e30 -> exact 0.
__device__ __forceinline__ float exp2r(float x) {
#if __has_builtin(__builtin_amdgcn_exp2f)
  return __builtin_amdgcn_exp2f(x);
#else
  float r; asm("v_exp_f32 %0, %1" : "=v"(r) : "v"(x)); return r;
#endif
}

// XCD-aware bijective block remap (T1). Dispatcher round-robins linear
// blockIdx across the 8 XCDs; this map hands each XCD a CONTIGUOUS chunk
// of the logical (x-fastest) enumeration so panel-sharing neighbor blocks
// hit the same per-XCD L2. Requires nwg % 8 == 0 (all our grids: 1280,
// 512, 512).
__device__ __forceinline__ int xcd_remap(int bid, int nwg) {
  return (bid & 7) * (nwg >> 3) + (bid >> 3);
}

// ---------- fused prep: x cvt (blocks 0..8191) + weight transposes ----------
__global__ __launch_bounds__(256) void prep_k(const float* __restrict__ x,
                                              const float* __restrict__ wq,
                                              const float* __restrict__ wk,
                                              const float* __restrict__ wv,
                                              const float* __restrict__ wo,
                                              bf16_t* __restrict__ xb,
                                              bf16_t* __restrict__ wcat,
                                              bf16_t* __restrict__ woT) {
  __shared__ float tile[32][33];
  const int bid = blockIdx.x;
  if (bid < 8192) {                      // x fp32 -> bf16
    int i = bid * 256 + threadIdx.x;
    float4 v = ((const float4*)x)[i];
    bf16x4 o = { (bf16_t)v.x, (bf16_t)v.y, (bf16_t)v.z, (bf16_t)v.w };
    ((bf16x4*)xb)[i] = o;
    return;
  }
  const int t = bid - 8192;              // weight transpose, 144*64 blocks
  const int kb = (t & 63) * 32;
  const int y = t >> 6;                  // 0..143
  const float* src; bf16_t* dst; int N; int nb;
  if (y < 64)      { src = wq; dst = wcat;                       N = 2048; nb = y; }
  else if (y < 72) { src = wk; dst = wcat + (long)2048 * 2048;   N = 256;  nb = y - 64; }
  else if (y < 80) { src = wv; dst = wcat + (long)2304 * 2048;   N = 256;  nb = y - 72; }
  else             { src = wo; dst = woT;                        N = 2048; nb = y - 80; }
  const int nb32 = nb * 32;
  const int tx = threadIdx.x & 31, ty = threadIdx.x >> 5;
  #pragma unroll
  for (int i = ty; i < 32; i += 8)
    tile[i][tx] = src[(long)(kb + i) * N + (nb32 + tx)];
  __syncthreads();
  #pragma unroll
  for (int i = ty; i < 32; i += 8)
    dst[(long)(nb32 + i) * 2048 + (kb + tx)] = (bf16_t)tile[tx][i];
}

// ---------- 128x128 split-K GEMM: 3-buf counted vmcnt + XCD swizzle --------
// 1D grid, logical id L enumerates m-tiles fastest -> each XCD owns whole
// B-panel columns (5 panels x 256KB, L2-resident per XCD).
__global__ __launch_bounds__(256) void gemm_splitk_k(const bf16_t* __restrict__ A,
                                                     const bf16_t* __restrict__ Bt,
                                                     bf16_t* __restrict__ P0,
                                                     bf16_t* __restrict__ P1,
                                                     int M, int N, int K) {
  __shared__ bf16_t As[3][128 * 32];
  __shared__ bf16_t Bs[3][128 * 32];
  const int tid = threadIdx.x, lane = tid & 63;
  const int wave = tid >> 6, wr = wave >> 1, wc = wave & 1;
  const int lrow = lane & 15, quad = lane >> 4;
  const int nbx = M >> 7, nby = N >> 7;
  const int L = xcd_remap(blockIdx.x, gridDim.x);
  const int bx = L % nbx, rest = L / nbx;
  const int by = rest % nby, z = rest / nby;
  const long m0 = (long)bx * 128, n0 = (long)by * 128;
  const int Kh = K >> 1;                    // 1024 per split

  f32x4 acc[4][4];
  #pragma unroll
  for (int i = 0; i < 4; i++)
    #pragma unroll
    for (int j = 0; j < 4; j++) acc[i][j] = (f32x4){0.f, 0.f, 0.f, 0.f};

  const int r0 = tid >> 2;
  const int cg = ((tid & 3) ^ (r0 & 3)) * 8;
  const bf16_t* Ag0 = A  + (m0 + r0) * (long)K + cg + (long)z * Kh;
  const bf16_t* Ag1 = Ag0 + 64 * (long)K;
  const bf16_t* Bg0 = Bt + (n0 + r0) * (long)K + cg + (long)z * Kh;
  const bf16_t* Bg1 = Bg0 + 64 * (long)K;
  const int swz = (quad ^ (lrow & 3)) * 8;   // frag chunk swizzle

  auto stage = [&](int tile, int bi) {
    const long k0 = (long)tile * 32;
    gld16(Ag0 + k0, &As[bi][tid * 8]);
    gld16(Ag1 + k0, &As[bi][2048 + tid * 8]);
    gld16(Bg0 + k0, &Bs[bi][tid * 8]);
    gld16(Bg1 + k0, &Bs[bi][2048 + tid * 8]);
  };
  auto compute = [&](int bi) {
    bf16x8 af[4], bfr[4];
    #pragma unroll
    for (int i = 0; i < 4; i++)
      af[i] = *(const bf16x8*)&As[bi][(wr * 64 + i * 16 + lrow) * 32 + swz];
    #pragma unroll
    for (int j = 0; j < 4; j++)
      bfr[j] = *(const bf16x8*)&Bs[bi][(wc * 64 + j * 16 + lrow) * 32 + swz];
    __builtin_amdgcn_s_setprio(1);
    #pragma unroll
    for (int i = 0; i < 4; i++)
      #pragma unroll
      for (int j = 0; j < 4; j++)
        acc[i][j] = MFMA16(af[i], bfr[j], acc[i][j]);
    __builtin_amdgcn_s_setprio(0);
  };

  const int nk = Kh >> 5;            // 32
  stage(0, 0); stage(1, 1);          // prologue: 8 loads in flight

  int cb = 0;                        // buffer holding tile t
  #pragma unroll 1
  for (int t = 0; t < nk - 2; t++) {
    asm volatile("s_waitcnt vmcnt(4)" ::: "memory");
    __builtin_amdgcn_s_barrier();
    int sb = cb + 2; if (sb >= 3) sb -= 3;
    stage(t + 2, sb);                // into buffer freed by tile t-1
    compute(cb);
    cb = (cb + 1 == 3) ? 0 : cb + 1;
  }
  asm volatile("s_waitcnt vmcnt(4)" ::: "memory");
  __builtin_amdgcn_s_barrier();
  compute(cb);
  cb = (cb + 1 == 3) ? 0 : cb + 1;
  asm volatile("s_waitcnt vmcnt(0)" ::: "memory");
  __builtin_amdgcn_s_barrier();
  compute(cb);

  bf16_t* P = z ? P1 : P0;
  #pragma unroll
  for (int i = 0; i < 4; i++) {
    #pragma unroll
    for (int r = 0; r < 4; r++) {
      long row = m0 + wr * 64 + i * 16 + quad * 4 + r;
      bf16_t* cp = P + row * N + n0 + wc * 64 + lrow;
      #pragma unroll
      for (int j = 0; j < 4; j++) cp[j * 16] = (bf16_t)acc[i][j][r];
    }
  }
}

// ---------- 128x128 MFMA GEMM (out-proj): quad-buffer vmcnt + XCD swizzle --
__global__ __launch_bounds__(256) void gemm128_k(const bf16_t* __restrict__ A,
                                                 const bf16_t* __restrict__ Bt,
                                                 float* __restrict__ C,
                                                 int M, int N, int K) {
  __shared__ bf16_t As[4][128 * 32];
  __shared__ bf16_t Bs[4][128 * 32];
  const int tid = threadIdx.x, lane = tid & 63;
  const int wave = tid >> 6, wr = wave >> 1, wc = wave & 1;
  const int lrow = lane & 15, quad = lane >> 4;
  const int nbx = M >> 7;
  const int L = xcd_remap(blockIdx.x, gridDim.x);
  const long m0 = (long)(L % nbx) * 128, n0 = (long)(L / nbx) * 128;

  f32x4 acc[4][4];
  #pragma unroll
  for (int i = 0; i < 4; i++)
    #pragma unroll
    for (int j = 0; j < 4; j++) acc[i][j] = (f32x4){0.f, 0.f, 0.f, 0.f};

  const int r0 = tid >> 2;
  const int cg = ((tid & 3) ^ (r0 & 3)) * 8;
  const bf16_t* Ag0 = A  + (m0 + r0) * (long)K + cg;
  const bf16_t* Ag1 = Ag0 + 64 * (long)K;
  const bf16_t* Bg0 = Bt + (n0 + r0) * (long)K + cg;
  const bf16_t* Bg1 = Bg0 + 64 * (long)K;
  const int swz = (quad ^ (lrow & 3)) * 8;   // frag chunk swizzle

  auto stage = [&](int tile) {
    const int bi = tile & 3;
    const long k0 = (long)tile * 32;
    gld16(Ag0 + k0, &As[bi][tid * 8]);
    gld16(Ag1 + k0, &As[bi][2048 + tid * 8]);
    gld16(Bg0 + k0, &Bs[bi][tid * 8]);
    gld16(Bg1 + k0, &Bs[bi][2048 + tid * 8]);
  };
  auto compute = [&](int tile) {
    const int bi = tile & 3;
    bf16x8 af[4], bfr[4];
    #pragma unroll
    for (int i = 0; i < 4; i++)
      af[i] = *(const bf16x8*)&As[bi][(wr * 64 + i * 16 + lrow) * 32 + swz];
    #pragma unroll
    for (int j = 0; j < 4; j++)
      bfr[j] = *(const bf16x8*)&Bs[bi][(wc * 64 + j * 16 + lrow) * 32 + swz];
    __builtin_amdgcn_s_setprio(1);
    #pragma unroll
    for (int i = 0; i < 4; i++)
      #pragma unroll
      for (int j = 0; j < 4; j++)
        acc[i][j] = MFMA16(af[i], bfr[j], acc[i][j]);
    __builtin_amdgcn_s_setprio(0);
  };

  const int nk = K >> 5;          // 64 for K=2048
  stage(0); stage(1); stage(2);   // prologue: 12 loads in flight

  #pragma unroll 1
  for (int t = 0; t < nk - 2; t++) {
    asm volatile("s_waitcnt vmcnt(8)" ::: "memory");
    __builtin_amdgcn_s_barrier();
    if (t + 3 < nk) stage(t + 3);        // into buffer freed by tile t-1
    compute(t);
  }
  asm volatile("s_waitcnt vmcnt(4)" ::: "memory");
  __builtin_amdgcn_s_barrier();
  compute(nk - 2);
  asm volatile("s_waitcnt vmcnt(0)" ::: "memory");
  __builtin_amdgcn_s_barrier();
  compute(nk - 1);

  #pragma unroll
  for (int i = 0; i < 4; i++) {
    #pragma unroll
    for (int r = 0; r < 4; r++) {
      long row = m0 + wr * 64 + i * 16 + quad * 4 + r;
      float* cp = C + row * N + n0 + wc * 64 + lrow;
      #pragma unroll
      for (int j = 0; j < 4; j++) cp[j * 16] = acc[i][j][r];
    }
  }
}

// ---------- fused post-projection: RoPE-repack (blocks 0..18431) + vtrans --
__global__ __launch_bounds__(256) void postproj_k(const bf16_t* __restrict__ P0,
                                                  const bf16_t* __restrict__ P1,
                                                  const float* __restrict__ freqs,
                                                  bf16_t* __restrict__ Qb,
                                                  bf16_t* __restrict__ Kb,
                                                  bf16_t* __restrict__ Vt) {
  __shared__ float tile[32][33];
  const int bid = blockIdx.x;
  if (bid < 18432) {                   // RoPE + repack Q,K
    const int PAIRS = (H_ + KVH_) * (HD_ / 2);   // 1152
    int idx = bid * 256 + threadIdx.x;
    int row = idx / PAIRS;
    int p   = idx % PAIRS;
    int s    = row & (S_ - 1);
    int b    = row >> 11;
    int head = p >> 5;        // 0..35 (0..31 = Q heads, 32..35 = K heads)
    int j    = p & 31;
    float2 f = ((const float2*)freqs)[s * 32 + j];   // (cos, sin)
    int col = (head < H_) ? (head * HD_ + 2 * j)
                          : (D_ + (head - H_) * HD_ + 2 * j);
    bf16x2 va = *(const bf16x2*)&P0[(long)row * QKVN + col];
    bf16x2 vb = *(const bf16x2*)&P1[(long)row * QKVN + col];
    float2 v = { (float)va[0] + (float)vb[0], (float)va[1] + (float)vb[1] };
    float2 o = { v.x * f.x - v.y * f.y, v.x * f.y + v.y * f.x };
    if (head < H_) {
      const float qs = 0.125f * 1.4426950408889634f;  // 1/sqrt(64) * log2(e)
      o.x *= qs; o.y *= qs;
      bf16x2 w = { (bf16_t)o.x, (bf16_t)o.y };
      *(bf16x2*)&Qb[(((long)(b * H_ + head) * S_ + s) * HD_) + 2 * j] = w;
    } else {
      bf16x2 w = { (bf16_t)o.x, (bf16_t)o.y };
      *(bf16x2*)&Kb[(((long)(b * KVH_ + (head - H_)) * S_ + s) * HD_) + 2 * j] = w;
    }
    return;
  }
  // V transpose: blocks 18432..19455 mapped to (s0:64, d0:2, bkv:8)
  const int t = bid - 18432;
  int s0 = (t & 63) * 32;
  int d0 = ((t >> 6) & 1) * 32;
  int bkv = t >> 7;                    // 0..7
  int b = bkv >> 2, kv = bkv & 3;
  int tx = threadIdx.x & 31, ty = threadIdx.x >> 5;
  const long base = (long)b * S_ * QKVN + D_ + KVH_ * HD_ + kv * HD_;
  #pragma unroll
  for (int i = ty; i < 32; i += 8) {
    const long idx = base + (long)(s0 + i) * QKVN + d0 + tx;
    tile[i][tx] = (float)P0[idx] + (float)P1[idx];
  }
  __syncthreads();
  #pragma unroll
  for (int i = ty; i < 32; i += 8)
    Vt[((long)bkv * HD_ + d0 + i) * S_ + s0 + tx] = (bf16_t)tile[tx][i];
}

// ---------- MFMA flash attention, v7 + XCD swizzle ----------
// 1D grid 512; logical L = x + 8*bh -> each XCD owns 8 whole bh columns,
// whose K/V working set (8 x 512KB = 4MB) exactly fills its private L2.
// Inner structure unchanged from R10 (tri-buffer counted-vmcnt pipeline,
// 4 waves x 32q, uniform pairing, in-register P, raw exp2, l via MFMA).
__global__ __launch_bounds__(256, 2) void fattn_k(const bf16_t* __restrict__ Qb,
                                                  const bf16_t* __restrict__ Kb,
                                                  const bf16_t* __restrict__ Vt,
                                                  bf16_t* __restrict__ attnb) {
  __shared__ bf16_t Ks[3][4096];   // K tile tri-buffer; prologue: Q tile
  __shared__ bf16_t Vs[3][4096];   // V^T tile tri-buffer

  const int L = xcd_remap(blockIdx.x, gridDim.x);
  const int x = L & 7, bh = L >> 3;            // x in [0,8)
  const int b = bh >> 5, h = bh & (H_ - 1), kv = h >> 3;
  const int tid = threadIdx.x, wave = tid >> 6, lane = tid & 63;
  const int c = lane & 31, hi = lane >> 5;

  const bf16_t* Kg = Kb + (long)(b * KVH_ + kv) * S_ * HD_;
  const bf16_t* Vg = Vt + (long)(b * KVH_ + kv) * HD_ * S_;

  // staging maps: slot idx holds chunk (row=idx>>3, ch=(idx&7)^(row&7))
  const int sr  = tid >> 3;                      // 0..31 (+32 on 2nd issue)
  const int scg = ((tid & 7) ^ (sr & 7)) * 8;
  const long qk0 = (long)sr * HD_ + scg;
  const long qk1 = qk0 + 32 * HD_;
  const long vo0 = (long)sr * S_ + scg;
  const long vo1 = vo0 + 32 * S_;

  // stage 64-key tile t into buffer bi (4 loads: 2 K + 2 V)
  auto stageKV = [&](int t, int bi) {
    const bf16_t* kp = Kg + (long)t * 64 * HD_;
    const bf16_t* vp = Vg + (long)t * 64;
    gld16(kp + qk0, &Ks[bi][tid * 8]);
    gld16(kp + qk1, &Ks[bi][2048 + tid * 8]);
    gld16(vp + vo0, &Vs[bi][tid * 8]);
    gld16(vp + vo1, &Vs[bi][2048 + tid * 8]);
  };

  bf16x8 ones8;
  #pragma unroll
  for (int i = 0; i < 8; i++) ones8[i] = (bf16_t)1.0f;

  #pragma unroll 1
  for (int half = 0; half < 2; half++) {
    const int qt = half ? (15 - x) : x;
    const int q0 = qt * 128;
    const int qw = q0 + wave * 32;               // this wave's 32 queries
    const bf16_t* Qg = Qb + ((long)bh * S_ + q0) * HD_;

    // ---- stage Q tile (128 x 64) into Ks[0..1], read B-frags, free buffer --
    __syncthreads();                  // protect Ks from previous half's reads
    gld16(Qg + qk0,            &Ks[0][tid * 8]);
    gld16(Qg + qk1,            &Ks[0][2048 + tid * 8]);
    gld16(Qg + 64 * HD_ + qk0, &Ks[1][tid * 8]);
    gld16(Qg + 64 * HD_ + qk1, &Ks[1][2048 + tid * 8]);
    __syncthreads();
    // B-frag (Q): lane (c,hi) holds Q[qw+c][ks*16 + hi*8 + j]
    const bf16_t* Qs = &Ks[0][0];
    bf16x8 bq[4];
    #pragma unroll
    for (int ks = 0; ks < 4; ks++)
      bq[ks] = *(const bf16x8*)&Qs[(wave * 32 + c) * 64 +
                                   (((ks * 2 + hi) ^ (c & 7)) * 8)];
    __syncthreads();

    f32x16 o32[2];
    o32[0] = (f32x16){}; o32[1] = (f32x16){};
    f32x16 lacc = (f32x16){};

    // one 64-key tile: QK both 32-key blocks -> per block exp2 -> permlane
    // redistribute -> PV + l-MFMA. All reg indices static (rule #20).
    auto softpv = [&](const bf16_t* Kc, const bf16_t* Vc, int qrel, bool masked) {
      const bool live0 = !(masked && 0 > qrel + 31);
      const bool live1 = !(masked && 32 > qrel + 31);
      f32x16 sv0 = (f32x16){}, sv1 = (f32x16){};
      __builtin_amdgcn_s_setprio(1);
      if (live0) {
        #pragma unroll
        for (int ks = 0; ks < 4; ks++) {
          bf16x8 ak = *(const bf16x8*)&Kc[(c) * 64 + (((ks * 2 + hi) ^ (c & 7)) * 8)];
          sv0 = MFMA32(ak, bq[ks], sv0);
        }
      }
      if (live1) {
        #pragma unroll
        for (int ks = 0; ks < 4; ks++) {
          bf16x8 ak = *(const bf16x8*)&Kc[(32 + c) * 64 + (((ks * 2 + hi) ^ (c & 7)) * 8)];
          sv1 = MFMA32(ak, bq[ks], sv1);
        }
      }
      __builtin_amdgcn_s_setprio(0);
      if (masked) {
        const int thr = qrel + c;
        #pragma unroll
        for (int r = 0; r < 16; r++) {
          const int key = (r & 3) + 8 * (r >> 2) + 4 * hi;
          if (key > thr)      sv0[r] = -1e30f;
          if (key > thr - 32) sv1[r] = -1e30f;
        }
      }
      // kB = 0
      if (live0) {
        int wa[4], wb[4];
        #pragma unroll
        for (int g = 0; g < 4; g++) {
          float p0 = exp2r(sv0[4 * g + 0]), p1 = exp2r(sv0[4 * g + 1]);
          float p2 = exp2r(sv0[4 * g + 2]), p3 = exp2r(sv0[4 * g + 3]);
          wa[g] = pkbf(p0, p1); wb[g] = pkbf(p2, p3);
        }
        #pragma unroll
        for (int ks16 = 0; ks16 < 2; ks16++) {
          int A0 = wa[2 * ks16], A1 = wa[2 * ks16 + 1];
          int B0 = wb[2 * ks16], B1 = wb[2 * ks16 + 1];
          asm("v_permlane32_swap_b32 %0, %1" : "+v"(A0), "+v"(A1));
          asm("v_permlane32_swap_b32 %0, %1" : "+v"(B0), "+v"(B1));
          i32x4 bpw = { A0, B0, A1, B1 };
          bf16x8 bp = __builtin_bit_cast(bf16x8, bpw);
          bf16x8 av0 = *(const bf16x8*)&Vc[(c) * 64 +
                         (((ks16 * 2 + hi) ^ (c & 7)) * 8)];
          bf16x8 av1 = *(const bf16x8*)&Vc[(32 + c) * 64 +
                         (((ks16 * 2 + hi) ^ (c & 7)) * 8)];
          __builtin_amdgcn_s_setprio(1);
          o32[0] = MFMA32(av0, bp, o32[0]);
          o32[1] = MFMA32(av1, bp, o32[1]);
          lacc   = MFMA32(ones8, bp, lacc);
          __builtin_amdgcn_s_setprio(0);
        }
      }
      // kB = 1
      if (live1) {
        int wa[4], wb[4];
        #pragma unroll
        for (int g = 0; g < 4; g++) {
          float p0 = exp2r(sv1[4 * g + 0]), p1 = exp2r(sv1[4 * g + 1]);
          float p2 = exp2r(sv1[4 * g + 2]), p3 = exp2r(sv1[4 * g + 3]);
          wa[g] = pkbf(p0, p1); wb[g] = pkbf(p2, p3);
        }
        #pragma unroll
        for (int ks16 = 0; ks16 < 2; ks16++) {
          int A0 = wa[2 * ks16], A1 = wa[2 * ks16 + 1];
          int B0 = wb[2 * ks16], B1 = wb[2 * ks16 + 1];
          asm("v_permlane32_swap_b32 %0, %1" : "+v"(A0), "+v"(A1));
          asm("v_permlane32_swap_b32 %0, %1" : "+v"(B0), "+v"(B1));
          i32x4 bpw = { A0, B0, A1, B1 };
          bf16x8 bp = __builtin_bit_cast(bf16x8, bpw);
          bf16x8 av0 = *(const bf16x8*)&Vc[(c) * 64 +
                         (((4 + ks16 * 2 + hi) ^ (c & 7)) * 8)];
          bf16x8 av1 = *(const bf16x8*)&Vc[(32 + c) * 64 +
                         (((4 + ks16 * 2 + hi) ^ (c & 7)) * 8)];
          __builtin_amdgcn_s_setprio(1);
          o32[0] = MFMA32(av0, bp, o32[0]);
          o32[1] = MFMA32(av1, bp, o32[1]);
          lacc   = MFMA32(ones8, bp, lacc);
          __builtin_amdgcn_s_setprio(0);
        }
      }
    };

    // ---- pipelined tile loop: T = ntm full tiles + 2 diagonal tiles ----
    const int ntm = 2 * qt;
    const int T = ntm + 2;
    stageKV(0, 0);                       // prologue: 8 loads in flight
    stageKV(1, 1);
    int cb = 0;                          // buffer holding tile t
    #pragma unroll 1
    for (int t = 0; t < T; t++) {
      if (t + 2 < T) {
        asm volatile("s_waitcnt vmcnt(4)" ::: "memory");  // tile t landed
        __builtin_amdgcn_s_barrier();
        int sb = cb + 2; if (sb >= 3) sb -= 3;
        stageKV(t + 2, sb);              // into buffer freed by tile t-1
      } else if (t + 1 < T) {
        asm volatile("s_waitcnt vmcnt(4)" ::: "memory");
        __builtin_amdgcn_s_barrier();
      } else {
        asm volatile("s_waitcnt vmcnt(0)" ::: "memory");
        __builtin_amdgcn_s_barrier();
      }
      softpv(&Ks[cb][0], &Vs[cb][0], qw - t * 64, t >= ntm);
      cb = (cb + 1 == 3) ? 0 : cb + 1;
    }

    // ---- epilogue: l = lacc[0] (full sum via MFMA-ones), normalize, store --
    const float inv = 1.f / lacc[0];
    const int query = qw + c;
    bf16_t* op = attnb + ((long)(b * S_ + query)) * D_ + h * HD_;
    #pragma unroll
    for (int db = 0; db < 2; db++) {
      #pragma unroll
      for (int g = 0; g < 4; g++) {
        bf16x4 w = { (bf16_t)(o32[db][4 * g + 0] * inv),
                     (bf16_t)(o32[db][4 * g + 1] * inv),
                     (bf16_t)(o32[db][4 * g + 2] * inv),
                     (bf16_t)(o32[db][4 * g + 3] * inv) };
        *(bf16x4*)&op[db * 32 + g * 8 + hi * 4] = w;
      }
    }
  }
}

extern "C" void kernel_launch(void* const* d_in, const int* in_sizes, int n_in,
                              void* d_out, int out_size, void* d_ws, size_t ws_size,
                              hipStream_t stream) {
  const float* x     = (const float*)d_in[0];
  const float* freqs = (const float*)d_in[1];
  // d_in[2] = mask: causal, implemented analytically
  const float* wq    = (const float*)d_in[3];
  const float* wk    = (const float*)d_in[4];
  const float* wv    = (const float*)d_in[5];
  const float* wo    = (const float*)d_in[6];
  float* out = (float*)d_out;

  // Workspace layout (77.6 MB), lifetime-aliased:
  //   [0,16.8M)       xb (bf16 x)           -> later Qb
  //   [16.8M,27.3M)   wcat (qkv weights^T)  -> later Kb (2.1M) + Vt (2.1M)
  //   [27.3M,35.65M)  woT
  //   [35.65M,56.6M)  P0 (bf16 QKV partial, K-half 0) -> later attnb (16.8M)
  //   [56.6M,77.6M)   P1 (bf16 QKV partial, K-half 1)
  char* ws = (char*)d_ws;
  bf16_t* xb    = (bf16_t*)(ws);
  bf16_t* wcat  = (bf16_t*)(ws + 16777216);
  bf16_t* woT   = (bf16_t*)(ws + 27262976);
  bf16_t* P0    = (bf16_t*)(ws + 35651584);
  bf16_t* P1    = (bf16_t*)(ws + 56623104);
  bf16_t* Qb    = xb;
  bf16_t* Kb    = (bf16_t*)(ws + 16777216);
  bf16_t* Vt    = (bf16_t*)(ws + 18874368);
  bf16_t* attnb = (bf16_t*)(ws + 35651584);   // overwrites P0 after postproj

  // 1) fused prep: x cvt + all weight transposes
  prep_k<<<8192 + 9216, 256, 0, stream>>>(x, wq, wk, wv, wo, xb, wcat, woT);

  // 2) fused QKV projection, split-K x2 -> bf16 partials P0,P1 (1280 blocks,
  //    XCD-swizzled 1D grid)
  gemm_splitk_k<<<1280, 256, 0, stream>>>(xb, wcat, P0, P1, 4096, QKVN, 2048);

  // 3) fused RoPE-repack + V transpose
  postproj_k<<<18432 + 1024, 256, 0, stream>>>(P0, P1, freqs, Qb, Kb, Vt);

  // 4) MFMA flash attention (v7, XCD-swizzled 1D grid)
  fattn_k<<<512, 256, 0, stream>>>(Qb, Kb, Vt, attnb);

  // 5) output projection (XCD-swizzled 1D grid)
  gemm128_k<<<512, 256, 0, stream>>>(attnb, woT, out, 4096, 2048, 2048);
}

// Round 12
// 289.152 us; speedup vs baseline: 1.0451x; 1.0451x over previous
//
#include <hip/hip_runtime.h>
#include <hip/hip_bf16.h>
#include <stdint.h>

// Problem constants
#define B_    2
#define S_    2048
#define D_    2048
#define H_    32
#define KVH_  4
#define HD_   64
#define QKVN  2560   // H*HD + 2*KVH*HD

typedef __bf16 bf16_t;
typedef __bf16 bf16x8 __attribute__((ext_vector_type(8)));
typedef __bf16 bf16x4 __attribute__((ext_vector_type(4)));
typedef __bf16 bf16x2 __attribute__((ext_vector_type(2)));
typedef float  f32x4  __attribute__((ext_vector_type(4)));
typedef float  f32x16 __attribute__((ext_vector_type(16)));
typedef int    i32x4  __attribute__((ext_vector_type(4)));

#define MFMA16(a, b, c) __builtin_amdgcn_mfma_f32_16x16x32_bf16(a, b, c, 0, 0, 0)
#define MFMA32(a, b, c) __builtin_amdgcn_mfma_f32_32x32x16_bf16(a, b, c, 0, 0, 0)

// async global->LDS, 16B per lane.
__device__ __forceinline__ void gld16(const void* g, void* l) {
  __builtin_amdgcn_global_load_lds(
      (const __attribute__((address_space(1))) uint32_t*)(uintptr_t)g,
      (__attribute__((address_space(3))) uint32_t*)(uint32_t)(uintptr_t)l,
      16, 0, 0);
}

// pack two f32 -> u32 of 2 bf16 (RNE via scalar casts)
__device__ __forceinline__ int pkbf(float a, float b) {
  bf16x2 t = { (bf16_t)a, (bf16_t)b };
  return __builtin_bit_cast(int, t);
}

// raw v_exp_f32 (2^x); scores bounded, masked lanes -1e30 -> exact 0.
__device__ __forceinline__ float exp2r(float x) {
#if __has_builtin(__builtin_amdgcn_exp2f)
  return __builtin_amdgcn_exp2f(x);
#else
  float r; asm("v_exp_f32 %0, %1" : "=v"(r) : "v"(x)); return r;
#endif
}

// NOTE (R11 lesson): do NOT XCD-remap these grids. Default linear dispatch
// round-robins bid%8 across XCDs; with x-fastest grids this pins each
// A-row panel (GEMMs) / each K/V working set (fattn) to one XCD's L2.
// An explicit "contiguous chunk per XCD" remap destroyed A-panel pinning
// (FETCH 54->131 MB, +3.5us). Default mapping is already optimal here.

// ---------- fused prep: x cvt (blocks 0..8191) + weight transposes ----------
__global__ __launch_bounds__(256) void prep_k(const float* __restrict__ x,
                                              const float* __restrict__ wq,
                                              const float* __restrict__ wk,
                                              const float* __restrict__ wv,
                                              const float* __restrict__ wo,
                                              bf16_t* __restrict__ xb,
                                              bf16_t* __restrict__ wcat,
                                              bf16_t* __restrict__ woT) {
  __shared__ float tile[32][33];
  const int bid = blockIdx.x;
  if (bid < 8192) {                      // x fp32 -> bf16
    int i = bid * 256 + threadIdx.x;
    float4 v = ((const float4*)x)[i];
    bf16x4 o = { (bf16_t)v.x, (bf16_t)v.y, (bf16_t)v.z, (bf16_t)v.w };
    ((bf16x4*)xb)[i] = o;
    return;
  }
  const int t = bid - 8192;              // weight transpose, 144*64 blocks
  const int kb = (t & 63) * 32;
  const int y = t >> 6;                  // 0..143
  const float* src; bf16_t* dst; int N; int nb;
  if (y < 64)      { src = wq; dst = wcat;                       N = 2048; nb = y; }
  else if (y < 72) { src = wk; dst = wcat + (long)2048 * 2048;   N = 256;  nb = y - 64; }
  else if (y < 80) { src = wv; dst = wcat + (long)2304 * 2048;   N = 256;  nb = y - 72; }
  else             { src = wo; dst = woT;                        N = 2048; nb = y - 80; }
  const int nb32 = nb * 32;
  const int tx = threadIdx.x & 31, ty = threadIdx.x >> 5;
  #pragma unroll
  for (int i = ty; i < 32; i += 8)
    tile[i][tx] = src[(long)(kb + i) * N + (nb32 + tx)];
  __syncthreads();
  #pragma unroll
  for (int i = ty; i < 32; i += 8)
    dst[(long)(nb32 + i) * 2048 + (kb + tx)] = (bf16_t)tile[tx][i];
}

// ---------- 128x128 split-K GEMM (R7-proven): 3-buf counted vmcnt ----------
__global__ __launch_bounds__(256) void gemm_splitk_k(const bf16_t* __restrict__ A,
                                                     const bf16_t* __restrict__ Bt,
                                                     bf16_t* __restrict__ P0,
                                                     bf16_t* __restrict__ P1,
                                                     int M, int N, int K) {
  __shared__ bf16_t As[3][128 * 32];
  __shared__ bf16_t Bs[3][128 * 32];
  const int tid = threadIdx.x, lane = tid & 63;
  const int wave = tid >> 6, wr = wave >> 1, wc = wave & 1;
  const int lrow = lane & 15, quad = lane >> 4;
  const long m0 = (long)blockIdx.x * 128, n0 = (long)blockIdx.y * 128;
  const int z = blockIdx.z;
  const int Kh = K >> 1;                    // 1024 per split

  f32x4 acc[4][4];
  #pragma unroll
  for (int i = 0; i < 4; i++)
    #pragma unroll
    for (int j = 0; j < 4; j++) acc[i][j] = (f32x4){0.f, 0.f, 0.f, 0.f};

  const int r0 = tid >> 2;
  const int cg = ((tid & 3) ^ (r0 & 3)) * 8;
  const bf16_t* Ag0 = A  + (m0 + r0) * (long)K + cg + (long)z * Kh;
  const bf16_t* Ag1 = Ag0 + 64 * (long)K;
  const bf16_t* Bg0 = Bt + (n0 + r0) * (long)K + cg + (long)z * Kh;
  const bf16_t* Bg1 = Bg0 + 64 * (long)K;
  const int swz = (quad ^ (lrow & 3)) * 8;   // frag chunk swizzle

  auto stage = [&](int tile, int bi) {
    const long k0 = (long)tile * 32;
    gld16(Ag0 + k0, &As[bi][tid * 8]);
    gld16(Ag1 + k0, &As[bi][2048 + tid * 8]);
    gld16(Bg0 + k0, &Bs[bi][tid * 8]);
    gld16(Bg1 + k0, &Bs[bi][2048 + tid * 8]);
  };
  auto compute = [&](int bi) {
    bf16x8 af[4], bfr[4];
    #pragma unroll
    for (int i = 0; i < 4; i++)
      af[i] = *(const bf16x8*)&As[bi][(wr * 64 + i * 16 + lrow) * 32 + swz];
    #pragma unroll
    for (int j = 0; j < 4; j++)
      bfr[j] = *(const bf16x8*)&Bs[bi][(wc * 64 + j * 16 + lrow) * 32 + swz];
    __builtin_amdgcn_s_setprio(1);
    #pragma unroll
    for (int i = 0; i < 4; i++)
      #pragma unroll
      for (int j = 0; j < 4; j++)
        acc[i][j] = MFMA16(af[i], bfr[j], acc[i][j]);
    __builtin_amdgcn_s_setprio(0);
  };

  const int nk = Kh >> 5;            // 32
  stage(0, 0); stage(1, 1);          // prologue: 8 loads in flight

  int cb = 0;                        // buffer holding tile t
  #pragma unroll 1
  for (int t = 0; t < nk - 2; t++) {
    asm volatile("s_waitcnt vmcnt(4)" ::: "memory");
    __builtin_amdgcn_s_barrier();
    int sb = cb + 2; if (sb >= 3) sb -= 3;
    stage(t + 2, sb);                // into buffer freed by tile t-1
    compute(cb);
    cb = (cb + 1 == 3) ? 0 : cb + 1;
  }
  asm volatile("s_waitcnt vmcnt(4)" ::: "memory");
  __builtin_amdgcn_s_barrier();
  compute(cb);
  cb = (cb + 1 == 3) ? 0 : cb + 1;
  asm volatile("s_waitcnt vmcnt(0)" ::: "memory");
  __builtin_amdgcn_s_barrier();
  compute(cb);

  bf16_t* P = z ? P1 : P0;
  #pragma unroll
  for (int i = 0; i < 4; i++) {
    #pragma unroll
    for (int r = 0; r < 4; r++) {
      long row = m0 + wr * 64 + i * 16 + quad * 4 + r;
      bf16_t* cp = P + row * N + n0 + wc * 64 + lrow;
      #pragma unroll
      for (int j = 0; j < 4; j++) cp[j * 16] = (bf16_t)acc[i][j][r];
    }
  }
}

// ---------- 128x128 MFMA GEMM, v2 (R5-proven): quad-buffer counted vmcnt ---
__global__ __launch_bounds__(256) void gemm128_k(const bf16_t* __restrict__ A,
                                                 const bf16_t* __restrict__ Bt,
                                                 float* __restrict__ C,
                                                 int M, int N, int K) {
  __shared__ bf16_t As[4][128 * 32];
  __shared__ bf16_t Bs[4][128 * 32];
  const int tid = threadIdx.x, lane = tid & 63;
  const int wave = tid >> 6, wr = wave >> 1, wc = wave & 1;
  const int lrow = lane & 15, quad = lane >> 4;
  const long m0 = (long)blockIdx.x * 128, n0 = (long)blockIdx.y * 128;

  f32x4 acc[4][4];
  #pragma unroll
  for (int i = 0; i < 4; i++)
    #pragma unroll
    for (int j = 0; j < 4; j++) acc[i][j] = (f32x4){0.f, 0.f, 0.f, 0.f};

  const int r0 = tid >> 2;
  const int cg = ((tid & 3) ^ (r0 & 3)) * 8;
  const bf16_t* Ag0 = A  + (m0 + r0) * (long)K + cg;
  const bf16_t* Ag1 = Ag0 + 64 * (long)K;
  const bf16_t* Bg0 = Bt + (n0 + r0) * (long)K + cg;
  const bf16_t* Bg1 = Bg0 + 64 * (long)K;
  const int swz = (quad ^ (lrow & 3)) * 8;   // frag chunk swizzle

  auto stage = [&](int tile) {
    const int bi = tile & 3;
    const long k0 = (long)tile * 32;
    gld16(Ag0 + k0, &As[bi][tid * 8]);
    gld16(Ag1 + k0, &As[bi][2048 + tid * 8]);
    gld16(Bg0 + k0, &Bs[bi][tid * 8]);
    gld16(Bg1 + k0, &Bs[bi][2048 + tid * 8]);
  };
  auto compute = [&](int tile) {
    const int bi = tile & 3;
    bf16x8 af[4], bfr[4];
    #pragma unroll
    for (int i = 0; i < 4; i++)
      af[i] = *(const bf16x8*)&As[bi][(wr * 64 + i * 16 + lrow) * 32 + swz];
    #pragma unroll
    for (int j = 0; j < 4; j++)
      bfr[j] = *(const bf16x8*)&Bs[bi][(wc * 64 + j * 16 + lrow) * 32 + swz];
    __builtin_amdgcn_s_setprio(1);
    #pragma unroll
    for (int i = 0; i < 4; i++)
      #pragma unroll
      for (int j = 0; j < 4; j++)
        acc[i][j] = MFMA16(af[i], bfr[j], acc[i][j]);
    __builtin_amdgcn_s_setprio(0);
  };

  const int nk = K >> 5;          // 64 for K=2048
  stage(0); stage(1); stage(2);   // prologue: 12 loads in flight

  #pragma unroll 1
  for (int t = 0; t < nk - 2; t++) {
    asm volatile("s_waitcnt vmcnt(8)" ::: "memory");
    __builtin_amdgcn_s_barrier();
    if (t + 3 < nk) stage(t + 3);        // into buffer freed by tile t-1
    compute(t);
  }
  asm volatile("s_waitcnt vmcnt(4)" ::: "memory");
  __builtin_amdgcn_s_barrier();
  compute(nk - 2);
  asm volatile("s_waitcnt vmcnt(0)" ::: "memory");
  __builtin_amdgcn_s_barrier();
  compute(nk - 1);

  #pragma unroll
  for (int i = 0; i < 4; i++) {
    #pragma unroll
    for (int r = 0; r < 4; r++) {
      long row = m0 + wr * 64 + i * 16 + quad * 4 + r;
      float* cp = C + row * N + n0 + wc * 64 + lrow;
      #pragma unroll
      for (int j = 0; j < 4; j++) cp[j * 16] = acc[i][j][r];
    }
  }
}

// ---------- fused post-projection: RoPE-repack (blocks 0..18431) + vtrans --
__global__ __launch_bounds__(256) void postproj_k(const bf16_t* __restrict__ P0,
                                                  const bf16_t* __restrict__ P1,
                                                  const float* __restrict__ freqs,
                                                  bf16_t* __restrict__ Qb,
                                                  bf16_t* __restrict__ Kb,
                                                  bf16_t* __restrict__ Vt) {
  __shared__ float tile[32][33];
  const int bid = blockIdx.x;
  if (bid < 18432) {                   // RoPE + repack Q,K
    const int PAIRS = (H_ + KVH_) * (HD_ / 2);   // 1152
    int idx = bid * 256 + threadIdx.x;
    int row = idx / PAIRS;
    int p   = idx % PAIRS;
    int s    = row & (S_ - 1);
    int b    = row >> 11;
    int head = p >> 5;        // 0..35 (0..31 = Q heads, 32..35 = K heads)
    int j    = p & 31;
    float2 f = ((const float2*)freqs)[s * 32 + j];   // (cos, sin)
    int col = (head < H_) ? (head * HD_ + 2 * j)
                          : (D_ + (head - H_) * HD_ + 2 * j);
    bf16x2 va = *(const bf16x2*)&P0[(long)row * QKVN + col];
    bf16x2 vb = *(const bf16x2*)&P1[(long)row * QKVN + col];
    float2 v = { (float)va[0] + (float)vb[0], (float)va[1] + (float)vb[1] };
    float2 o = { v.x * f.x - v.y * f.y, v.x * f.y + v.y * f.x };
    if (head < H_) {
      const float qs = 0.125f * 1.4426950408889634f;  // 1/sqrt(64) * log2(e)
      o.x *= qs; o.y *= qs;
      bf16x2 w = { (bf16_t)o.x, (bf16_t)o.y };
      *(bf16x2*)&Qb[(((long)(b * H_ + head) * S_ + s) * HD_) + 2 * j] = w;
    } else {
      bf16x2 w = { (bf16_t)o.x, (bf16_t)o.y };
      *(bf16x2*)&Kb[(((long)(b * KVH_ + (head - H_)) * S_ + s) * HD_) + 2 * j] = w;
    }
    return;
  }
  // V transpose: blocks 18432..19455 mapped to (s0:64, d0:2, bkv:8)
  const int t = bid - 18432;
  int s0 = (t & 63) * 32;
  int d0 = ((t >> 6) & 1) * 32;
  int bkv = t >> 7;                    // 0..7
  int b = bkv >> 2, kv = bkv & 3;
  int tx = threadIdx.x & 31, ty = threadIdx.x >> 5;
  const long base = (long)b * S_ * QKVN + D_ + KVH_ * HD_ + kv * HD_;
  #pragma unroll
  for (int i = ty; i < 32; i += 8) {
    const long idx = base + (long)(s0 + i) * QKVN + d0 + tx;
    tile[i][tx] = (float)P0[idx] + (float)P1[idx];
  }
  __syncthreads();
  #pragma unroll
  for (int i = ty; i < 32; i += 8)
    Vt[((long)bkv * HD_ + d0 + i) * S_ + s0 + tx] = (bf16_t)tile[tx][i];
}

// ---------- MFMA flash attention, v5 (best measured; R9 config) ----------
// 4 waves x 32q, uniform work pairing, dbuf prefetch 1 barrier/tile,
// in-register P via permlane32_swap, raw exp2, l via MFMA-ones.
// Default grid (8,64): bid%8 = x -> each XCD owns its full 4MB K/V set.
__global__ __launch_bounds__(256, 2) void fattn_k(const bf16_t* __restrict__ Qb,
                                                  const bf16_t* __restrict__ Kb,
                                                  const bf16_t* __restrict__ Vt,
                                                  bf16_t* __restrict__ attnb) {
  __shared__ bf16_t Ks[2][4096];   // K tile dbuf; per-half prologue: Q tile
  __shared__ bf16_t Vs[2][4096];   // V^T tile dbuf

  const int x = blockIdx.x, yy = blockIdx.y;   // x in [0,8)
  const int bh = yy;
  const int b = bh >> 5, h = bh & (H_ - 1), kv = h >> 3;
  const int tid = threadIdx.x, wave = tid >> 6, lane = tid & 63;
  const int c = lane & 31, hi = lane >> 5;

  const bf16_t* Kg = Kb + (long)(b * KVH_ + kv) * S_ * HD_;
  const bf16_t* Vg = Vt + (long)(b * KVH_ + kv) * HD_ * S_;

  // staging maps: slot idx holds chunk (row=idx>>3, ch=(idx&7)^(row&7))
  const int sr  = tid >> 3;                      // 0..31 (+32 on 2nd issue)
  const int scg = ((tid & 7) ^ (sr & 7)) * 8;
  const long qk0 = (long)sr * HD_ + scg;
  const long qk1 = qk0 + 32 * HD_;
  const long vo0 = (long)sr * S_ + scg;
  const long vo1 = vo0 + 32 * S_;

  bf16_t* k0d = &Ks[0][tid * 8]; bf16_t* k0d2 = k0d + 2048;
  bf16_t* k1d = &Ks[1][tid * 8]; bf16_t* k1d2 = k1d + 2048;
  bf16_t* v0d = &Vs[0][tid * 8]; bf16_t* v0d2 = v0d + 2048;
  bf16_t* v1d = &Vs[1][tid * 8]; bf16_t* v1d2 = v1d + 2048;

  bf16x8 ones8;
  #pragma unroll
  for (int i = 0; i < 8; i++) ones8[i] = (bf16_t)1.0f;

  #pragma unroll 1
  for (int half = 0; half < 2; half++) {
    const int qt = half ? (15 - x) : x;
    const int q0 = qt * 128;
    const int qw = q0 + wave * 32;               // this wave's 32 queries
    const bf16_t* Qg = Qb + ((long)bh * S_ + q0) * HD_;

    // ---- stage Q tile (128 x 64) into Ks[0..1], read B-frags, free buffer --
    __syncthreads();                  // protect Ks from previous half's reads
    gld16(Qg + qk0,            k0d);
    gld16(Qg + qk1,            k0d2);
    gld16(Qg + 64 * HD_ + qk0, k1d);
    gld16(Qg + 64 * HD_ + qk1, k1d2);
    __syncthreads();
    // B-frag (Q): lane (c,hi) holds Q[qw+c][ks*16 + hi*8 + j]
    const bf16_t* Qs = &Ks[0][0];
    bf16x8 bq[4];
    #pragma unroll
    for (int ks = 0; ks < 4; ks++)
      bq[ks] = *(const bf16x8*)&Qs[(wave * 32 + c) * 64 +
                                   (((ks * 2 + hi) ^ (c & 7)) * 8)];
    __syncthreads();

    // ---- prologue: stage K/V tile 0 -> buf 0 ----
    const bf16_t* kgp = Kg;
    const bf16_t* vgp = Vg;
    gld16(kgp + qk0, k0d); gld16(kgp + qk1, k0d2);
    gld16(vgp + vo0, v0d); gld16(vgp + vo1, v0d2);

    f32x16 o32[2];
    o32[0] = (f32x16){}; o32[1] = (f32x16){};
    f32x16 lacc = (f32x16){};

    // one 64-key tile: QK both 32-key blocks -> per block exp2 -> permlane
    // redistribute -> PV + l-MFMA. All indices static (rule #20).
    auto softpv = [&](const bf16_t* Kc, const bf16_t* Vc, int qrel, bool masked) {
      const bool live0 = !(masked && 0 > qrel + 31);
      const bool live1 = !(masked && 32 > qrel + 31);
      f32x16 sv0 = (f32x16){}, sv1 = (f32x16){};
      __builtin_amdgcn_s_setprio(1);
      if (live0) {
        #pragma unroll
        for (int ks = 0; ks < 4; ks++) {
          bf16x8 ak = *(const bf16x8*)&Kc[(c) * 64 + (((ks * 2 + hi) ^ (c & 7)) * 8)];
          sv0 = MFMA32(ak, bq[ks], sv0);
        }
      }
      if (live1) {
        #pragma unroll
        for (int ks = 0; ks < 4; ks++) {
          bf16x8 ak = *(const bf16x8*)&Kc[(32 + c) * 64 + (((ks * 2 + hi) ^ (c & 7)) * 8)];
          sv1 = MFMA32(ak, bq[ks], sv1);
        }
      }
      __builtin_amdgcn_s_setprio(0);
      if (masked) {
        const int thr = qrel + c;
        #pragma unroll
        for (int r = 0; r < 16; r++) {
          const int key = (r & 3) + 8 * (r >> 2) + 4 * hi;
          if (key > thr)      sv0[r] = -1e30f;
          if (key > thr - 32) sv1[r] = -1e30f;
        }
      }
      // kB = 0
      if (live0) {
        int wa[4], wb[4];
        #pragma unroll
        for (int g = 0; g < 4; g++) {
          float p0 = exp2r(sv0[4 * g + 0]), p1 = exp2r(sv0[4 * g + 1]);
          float p2 = exp2r(sv0[4 * g + 2]), p3 = exp2r(sv0[4 * g + 3]);
          wa[g] = pkbf(p0, p1); wb[g] = pkbf(p2, p3);
        }
        #pragma unroll
        for (int ks16 = 0; ks16 < 2; ks16++) {
          int A0 = wa[2 * ks16], A1 = wa[2 * ks16 + 1];
          int B0 = wb[2 * ks16], B1 = wb[2 * ks16 + 1];
          asm("v_permlane32_swap_b32 %0, %1" : "+v"(A0), "+v"(A1));
          asm("v_permlane32_swap_b32 %0, %1" : "+v"(B0), "+v"(B1));
          i32x4 bpw = { A0, B0, A1, B1 };
          bf16x8 bp = __builtin_bit_cast(bf16x8, bpw);
          bf16x8 av0 = *(const bf16x8*)&Vc[(c) * 64 +
                         (((ks16 * 2 + hi) ^ (c & 7)) * 8)];
          bf16x8 av1 = *(const bf16x8*)&Vc[(32 + c) * 64 +
                         (((ks16 * 2 + hi) ^ (c & 7)) * 8)];
          __builtin_amdgcn_s_setprio(1);
          o32[0] = MFMA32(av0, bp, o32[0]);
          o32[1] = MFMA32(av1, bp, o32[1]);
          lacc   = MFMA32(ones8, bp, lacc);
          __builtin_amdgcn_s_setprio(0);
        }
      }
      // kB = 1
      if (live1) {
        int wa[4], wb[4];
        #pragma unroll
        for (int g = 0; g < 4; g++) {
          float p0 = exp2r(sv1[4 * g + 0]), p1 = exp2r(sv1[4 * g + 1]);
          float p2 = exp2r(sv1[4 * g + 2]), p3 = exp2r(sv1[4 * g + 3]);
          wa[g] = pkbf(p0, p1); wb[g] = pkbf(p2, p3);
        }
        #pragma unroll
        for (int ks16 = 0; ks16 < 2; ks16++) {
          int A0 = wa[2 * ks16], A1 = wa[2 * ks16 + 1];
          int B0 = wb[2 * ks16], B1 = wb[2 * ks16 + 1];
          asm("v_permlane32_swap_b32 %0, %1" : "+v"(A0), "+v"(A1));
          asm("v_permlane32_swap_b32 %0, %1" : "+v"(B0), "+v"(B1));
          i32x4 bpw = { A0, B0, A1, B1 };
          bf16x8 bp = __builtin_bit_cast(bf16x8, bpw);
          bf16x8 av0 = *(const bf16x8*)&Vc[(c) * 64 +
                         (((4 + ks16 * 2 + hi) ^ (c & 7)) * 8)];
          bf16x8 av1 = *(const bf16x8*)&Vc[(32 + c) * 64 +
                         (((4 + ks16 * 2 + hi) ^ (c & 7)) * 8)];
          __builtin_amdgcn_s_setprio(1);
          o32[0] = MFMA32(av0, bp, o32[0]);
          o32[1] = MFMA32(av1, bp, o32[1]);
          lacc   = MFMA32(ones8, bp, lacc);
          __builtin_amdgcn_s_setprio(0);
        }
      }
    };

    // ---- main loop: full (unmasked) tiles 0 .. 2*qt-1, 2x unrolled dbuf ----
    const int ntm = 2 * qt;
    #pragma unroll 1
    for (int t = 0; t < ntm; t += 2) {
      __syncthreads();                       // drains stage of buf0 (tile t)
      kgp += 64 * HD_; vgp += 64;            // tile t+1 -> buf1
      gld16(kgp + qk0, k1d); gld16(kgp + qk1, k1d2);
      gld16(vgp + vo0, v1d); gld16(vgp + vo1, v1d2);
      softpv(&Ks[0][0], &Vs[0][0], 0, false);
      __syncthreads();                       // drains stage of buf1 (tile t+1)
      kgp += 64 * HD_; vgp += 64;            // tile t+2 -> buf0
      gld16(kgp + qk0, k0d); gld16(kgp + qk1, k0d2);
      gld16(vgp + vo0, v0d); gld16(vgp + vo1, v0d2);
      softpv(&Ks[1][0], &Vs[1][0], 0, false);
    }

    // ---- diagonal tiles ntm (buf0) and ntm+1 (buf1), masked ----
    __syncthreads();
    kgp += 64 * HD_; vgp += 64;              // tile ntm+1 -> buf1
    gld16(kgp + qk0, k1d); gld16(kgp + qk1, k1d2);
    gld16(vgp + vo0, v1d); gld16(vgp + vo1, v1d2);
    softpv(&Ks[0][0], &Vs[0][0], qw - ntm * 64, true);
    __syncthreads();
    softpv(&Ks[1][0], &Vs[1][0], qw - (ntm + 1) * 64, true);

    // ---- epilogue: l = lacc[0] (full sum via MFMA-ones), normalize, store --
    const float inv = 1.f / lacc[0];
    const int query = qw + c;
    bf16_t* op = attnb + ((long)(b * S_ + query)) * D_ + h * HD_;
    #pragma unroll
    for (int db = 0; db < 2; db++) {
      #pragma unroll
      for (int g = 0; g < 4; g++) {
        bf16x4 w = { (bf16_t)(o32[db][4 * g + 0] * inv),
                     (bf16_t)(o32[db][4 * g + 1] * inv),
                     (bf16_t)(o32[db][4 * g + 2] * inv),
                     (bf16_t)(o32[db][4 * g + 3] * inv) };
        *(bf16x4*)&op[db * 32 + g * 8 + hi * 4] = w;
      }
    }
  }
}

extern "C" void kernel_launch(void* const* d_in, const int* in_sizes, int n_in,
                              void* d_out, int out_size, void* d_ws, size_t ws_size,
                              hipStream_t stream) {
  const float* x     = (const float*)d_in[0];
  const float* freqs = (const float*)d_in[1];
  // d_in[2] = mask: causal, implemented analytically
  const float* wq    = (const float*)d_in[3];
  const float* wk    = (const float*)d_in[4];
  const float* wv    = (const float*)d_in[5];
  const float* wo    = (const float*)d_in[6];
  float* out = (float*)d_out;

  // Workspace layout (77.6 MB), lifetime-aliased:
  //   [0,16.8M)       xb (bf16 x)           -> later Qb
  //   [16.8M,27.3M)   wcat (qkv weights^T)  -> later Kb (2.1M) + Vt (2.1M)
  //   [27.3M,35.65M)  woT
  //   [35.65M,56.6M)  P0 (bf16 QKV partial, K-half 0) -> later attnb (16.8M)
  //   [56.6M,77.6M)   P1 (bf16 QKV partial, K-half 1)
  char* ws = (char*)d_ws;
  bf16_t* xb    = (bf16_t*)(ws);
  bf16_t* wcat  = (bf16_t*)(ws + 16777216);
  bf16_t* woT   = (bf16_t*)(ws + 27262976);
  bf16_t* P0    = (bf16_t*)(ws + 35651584);
  bf16_t* P1    = (bf16_t*)(ws + 56623104);
  bf16_t* Qb    = xb;
  bf16_t* Kb    = (bf16_t*)(ws + 16777216);
  bf16_t* Vt    = (bf16_t*)(ws + 18874368);
  bf16_t* attnb = (bf16_t*)(ws + 35651584);   // overwrites P0 after postproj

  // 1) fused prep: x cvt + all weight transposes
  prep_k<<<8192 + 9216, 256, 0, stream>>>(x, wq, wk, wv, wo, xb, wcat, woT);

  // 2) fused QKV projection, split-K x2 -> bf16 partials P0,P1
  { dim3 g(32, 20, 2); gemm_splitk_k<<<g, 256, 0, stream>>>(xb, wcat, P0, P1,
                                                            4096, QKVN, 2048); }

  // 3) fused RoPE-repack + V transpose
  postproj_k<<<18432 + 1024, 256, 0, stream>>>(P0, P1, freqs, Qb, Kb, Vt);

  // 4) MFMA flash attention (v5)
  { dim3 g(8, 64); fattn_k<<<g, 256, 0, stream>>>(Qb, Kb, Vt, attnb); }

  // 5) output projection: out[4096][2048] = attnb @ woT^T
  { dim3 g(32, 16); gemm128_k<<<g, 256, 0, stream>>>(attnb, woT, out, 4096, 2048, 2048); }
}